// Round 1
// baseline (1472.329 us; speedup 1.0000x reference)
//
#include <hip/hip_runtime.h>

// MAF forward: 32 autoregressive MADE steps, fully fused.
// N=65536 samples, D=32, H=1024, C=64.
// ws layout (bf16 as u16):
//   [0      .. 32768)  W1mT [h=1024][d=32]   = W1[d][h]*mask1
//   [32768  .. 98304)  W2mT [c=64][h=1024]   = W2[h][c]*mask2   (c = d*2+p)
//   [98304  ..163840)  WcT  [h=1024][c=64]   = Wc[c][h]

#define NS 65536
#define DD_ 32
#define HH 1024
#define CC 64

typedef __attribute__((ext_vector_type(8))) short short8;
typedef __attribute__((ext_vector_type(4))) float f32x4;

__device__ inline unsigned short f2bf(float f) {
  unsigned int u = __builtin_bit_cast(unsigned int, f);
  u += 0x7fffu + ((u >> 16) & 1u);          // RNE
  return (unsigned short)(u >> 16);
}
__device__ inline unsigned int pack2bf(float a, float b) {
  return (unsigned int)f2bf(a) | ((unsigned int)f2bf(b) << 16);
}
__device__ inline float bflo(unsigned int p) {
  unsigned int u = p << 16; return __builtin_bit_cast(float, u);
}
__device__ inline float bfhi(unsigned int p) {
  unsigned int u = p & 0xffff0000u; return __builtin_bit_cast(float, u);
}
// tanh(x) = 1 - 2/(1+e^{2x}); saturates correctly for |x| large (e^{2x}->inf or 0)
__device__ inline float tanh_fast(float x) {
  float t = __expf(2.0f * x);
  float r = __builtin_amdgcn_rcpf(t + 1.0f);
  return fmaf(-2.0f, r, 1.0f);
}

__global__ void maf_prep(const float* __restrict__ W1, const float* __restrict__ Wc,
                         const float* __restrict__ W2, unsigned short* __restrict__ ws) {
  int t = blockIdx.x * blockDim.x + threadIdx.x;     // 0 .. 163839
  if (t < 32768) {                                   // W1mT [h][d]
    int h = t >> 5, d = t & 31;
    int deg = h % 31 + 1;                            // hid_deg
    float v = (deg >= d + 1) ? W1[(size_t)d * HH + h] : 0.f;
    ws[t] = f2bf(v);
  } else if (t < 98304) {                            // W2mT [c][h]
    int i = t - 32768;
    int c = i >> 10, h = i & 1023;
    int deg = h % 31 + 1;
    float v = (((c >> 1) + 1) > deg) ? W2[(size_t)h * 64 + c] : 0.f;
    ws[t] = f2bf(v);
  } else {                                           // WcT [h][c]
    int i = t - 98304;
    int h = i >> 6, c = i & 63;
    ws[t] = f2bf(Wc[(size_t)c * HH + h]);
  }
}

__global__ __launch_bounds__(512, 4) void maf_main(
    const float* __restrict__ x, const float* __restrict__ ctx,
    const float* __restrict__ b1, const float* __restrict__ b2,
    const unsigned short* __restrict__ ws, float* __restrict__ out)
{
  // LDS: 66048 + 2560 + 8448 + 4608 = 81664 B  -> 2 blocks/CU (163328 <= 163840)
  __shared__ __align__(16) unsigned short hidb[32][1032];  // hid bf16, +8 pad (keeps 16B row align)
  __shared__ __align__(16) unsigned short ybf[32][40];     // y bf16, +8 pad
  __shared__ __align__(16) float Pp[32][66];               // params [s][c], c = 2d+p
  __shared__ __align__(16) unsigned short ctxb[32][72];    // ctx tile bf16

  const unsigned short* W1mT = ws;            // [1024][32]
  const unsigned short* W2mT = ws + 32768;    // [64][1024]
  const unsigned short* WcT  = ws + 98304;    // [1024][64]

  const int tid  = threadIdx.x;
  const int lane = tid & 63;
  const int w    = tid >> 6;        // wave 0..7
  const int l15  = lane & 15;
  const int lk   = lane >> 4;       // 0..3
  const int s0   = blockIdx.x * 32;

  // ---- stage ctx tile (bf16) and zero y ----
  {
    int s = tid >> 4, c4 = (tid & 15) << 2;
    const float* src = ctx + (size_t)(s0 + s) * CC + c4;
    unsigned short* dst = &ctxb[s][c4];
#pragma unroll
    for (int q = 0; q < 4; ++q) dst[q] = f2bf(src[q]);
  }
  for (int i = tid; i < 640; i += 512)
    reinterpret_cast<unsigned int*>(&ybf[0][0])[i] = 0u;

  // epilogue-role constants (thread -> (sample es, dims ej, ej+16))
  const int es = tid & 31, ej = tid >> 5;
  float xr0 = x[(size_t)(s0 + es) * DD_ + ej];
  float xr1 = x[(size_t)(s0 + es) * DD_ + ej + 16];
  float b2e0 = b2[2 * ej],        b2o0 = b2[2 * ej + 1];
  float b2e1 = b2[2 * (ej + 16)], b2o1 = b2[2 * (ej + 16) + 1];

  __syncthreads();

  // ---- WcH = ctx@Wc + b1, kept in registers (packed bf16), C/D layout ----
  unsigned int wchp[2][8][2];
#pragma unroll 2
  for (int j = 0; j < 8; ++j) {
    int hcol = (w * 8 + j) * 16 + l15;
    f32x4 acc0 = {0.f, 0.f, 0.f, 0.f}, acc1 = {0.f, 0.f, 0.f, 0.f};
#pragma unroll
    for (int ks = 0; ks < 2; ++ks) {
      int k0 = ks * 32 + lk * 8;
      short8 a0 = *reinterpret_cast<const short8*>(&ctxb[l15][k0]);
      short8 a1 = *reinterpret_cast<const short8*>(&ctxb[16 + l15][k0]);
      short8 b  = *reinterpret_cast<const short8*>(WcT + (size_t)hcol * 64 + k0);
      acc0 = __builtin_amdgcn_mfma_f32_16x16x32_bf16(a0, b, acc0, 0, 0, 0);
      acc1 = __builtin_amdgcn_mfma_f32_16x16x32_bf16(a1, b, acc1, 0, 0, 0);
    }
    float b1v = b1[hcol];
    wchp[0][j][0] = pack2bf(acc0[0] + b1v, acc0[1] + b1v);
    wchp[0][j][1] = pack2bf(acc0[2] + b1v, acc0[3] + b1v);
    wchp[1][j][0] = pack2bf(acc1[0] + b1v, acc1[1] + b1v);
    wchp[1][j][1] = pack2bf(acc1[2] + b1v, acc1[3] + b1v);
  }

  const int nt2 = w & 3, kh = w >> 2;     // GEMM2 ownership: (output col tile, K half)
  const int col = nt2 * 16 + l15;

  for (int step = 0; step < 32; ++step) {
    // ---- GEMM1: hid = tanh(y @ W1m + WcH) -> LDS bf16 ----
    {
      short8 a0 = *reinterpret_cast<const short8*>(&ybf[l15][lk * 8]);
      short8 a1 = *reinterpret_cast<const short8*>(&ybf[16 + l15][lk * 8]);
#pragma unroll 4
      for (int j = 0; j < 8; ++j) {
        int hcol = (w * 8 + j) * 16 + l15;
        short8 b = *reinterpret_cast<const short8*>(W1mT + (size_t)hcol * 32 + lk * 8);
        f32x4 z = {0.f, 0.f, 0.f, 0.f};
        f32x4 acc0 = __builtin_amdgcn_mfma_f32_16x16x32_bf16(a0, b, z, 0, 0, 0);
        f32x4 acc1 = __builtin_amdgcn_mfma_f32_16x16x32_bf16(a1, b, z, 0, 0, 0);
#pragma unroll
        for (int rp = 0; rp < 2; ++rp) {
          int r0 = 4 * lk + 2 * rp;
          hidb[r0 + 0][hcol]      = f2bf(tanh_fast(acc0[2 * rp + 0] + bflo(wchp[0][j][rp])));
          hidb[r0 + 1][hcol]      = f2bf(tanh_fast(acc0[2 * rp + 1] + bfhi(wchp[0][j][rp])));
          hidb[16 + r0 + 0][hcol] = f2bf(tanh_fast(acc1[2 * rp + 0] + bflo(wchp[1][j][rp])));
          hidb[16 + r0 + 1][hcol] = f2bf(tanh_fast(acc1[2 * rp + 1] + bfhi(wchp[1][j][rp])));
        }
      }
    }
    __syncthreads();

    // ---- GEMM2: params = hid @ W2m   (k-split across wave pairs) ----
    f32x4 p0 = {0.f, 0.f, 0.f, 0.f}, p1 = {0.f, 0.f, 0.f, 0.f};
#pragma unroll 4
    for (int ks = 0; ks < 16; ++ks) {
      int k0 = kh * 512 + ks * 32 + lk * 8;
      short8 a0 = *reinterpret_cast<const short8*>(&hidb[l15][k0]);
      short8 a1 = *reinterpret_cast<const short8*>(&hidb[16 + l15][k0]);
      short8 b  = *reinterpret_cast<const short8*>(W2mT + (size_t)col * 1024 + k0);
      p0 = __builtin_amdgcn_mfma_f32_16x16x32_bf16(a0, b, p0, 0, 0, 0);
      p1 = __builtin_amdgcn_mfma_f32_16x16x32_bf16(a1, b, p1, 0, 0, 0);
    }
    if (kh == 0) {
#pragma unroll
      for (int r = 0; r < 4; ++r) {
        Pp[4 * lk + r][col]      = p0[r];
        Pp[16 + 4 * lk + r][col] = p1[r];
      }
    }
    __syncthreads();
    if (kh == 1) {
#pragma unroll
      for (int r = 0; r < 4; ++r) {
        Pp[4 * lk + r][col]      += p0[r];
        Pp[16 + 4 * lk + r][col] += p1[r];
      }
    }
    __syncthreads();

    // ---- epilogue: y = x*exp(log_scale) + shift ----
    const bool last = (step == 31);
    {
      float sh0 = Pp[es][2 * ej]      + b2e0;
      float ls0 = Pp[es][2 * ej + 1]  + b2o0;
      float yv0 = fmaf(xr0, __expf(ls0), sh0);
      ybf[es][ej] = f2bf(yv0);
      float sh1 = Pp[es][2 * (ej + 16)]     + b2e1;
      float ls1 = Pp[es][2 * (ej + 16) + 1] + b2o1;
      float yv1 = fmaf(xr1, __expf(ls1), sh1);
      ybf[es][ej + 16] = f2bf(yv1);
      if (last) {
        out[(size_t)(s0 + es) * DD_ + ej]      = yv0;
        out[(size_t)(s0 + es) * DD_ + ej + 16] = yv1;
      }
    }
    if (last && tid < 32) {
      float acc = 0.f;
#pragma unroll
      for (int d = 0; d < 32; ++d) acc += Pp[tid][2 * d + 1] + b2[2 * d + 1];
      out[(size_t)NS * DD_ + s0 + tid] = acc;    // log_det (last step's log_scale summed)
    }
    __syncthreads();
  }
}

extern "C" void kernel_launch(void* const* d_in, const int* in_sizes, int n_in,
                              void* d_out, int out_size, void* d_ws, size_t ws_size,
                              hipStream_t stream) {
  (void)in_sizes; (void)n_in; (void)out_size; (void)ws_size;
  const float* x   = (const float*)d_in[0];
  const float* ctx = (const float*)d_in[1];
  const float* W1  = (const float*)d_in[2];
  const float* b1  = (const float*)d_in[3];
  const float* Wc  = (const float*)d_in[4];
  const float* W2  = (const float*)d_in[5];
  const float* b2  = (const float*)d_in[6];
  unsigned short* ws = (unsigned short*)d_ws;
  float* out = (float*)d_out;

  maf_prep<<<640, 256, 0, stream>>>(W1, Wc, W2, ws);
  maf_main<<<2048, 512, 0, stream>>>(x, ctx, b1, b2, ws, out);
}